// Round 1
// baseline (82.925 us; speedup 1.0000x reference)
//
#include <hip/hip_runtime.h>

// WeightedAggregator: out[b,d] = sum_k w[b,k] * features[idx[b,k], d] / sum_k w[b,k]
// B=100000, K=10, V=200000, D=128, all float32.
//
// Layout: 32 lanes per output row, each lane holds one float4 (32*16B = 512B = D row).
// 256-thread block = 8 rows; grid = ceil(B/8). All K gathers issued unrolled so
// the compiler keeps 10 global_load_dwordx4 in flight per lane.

#define K_N   10
#define D_DIM 128

__global__ __launch_bounds__(256) void WeightedAggregator_kernel(
    const float* __restrict__ features,
    const float* __restrict__ weights,
    const int*   __restrict__ neigh_idx,
    float*       __restrict__ out,
    int B)
{
    const int group = threadIdx.x >> 5;                 // 8 row-groups per block
    const int lane  = threadIdx.x & 31;                 // 32 lanes per row
    const int b     = blockIdx.x * 8 + group;
    if (b >= B) return;

    // Per-row weights + indices (same addresses across the 32-lane group ->
    // cache broadcast; cheap).
    float w[K_N];
    int   idx[K_N];
#pragma unroll
    for (int k = 0; k < K_N; ++k) {
        w[k]   = weights[b * K_N + k];
        idx[k] = neigh_idx[b * K_N + k];
    }

    float wsum = 0.f;
#pragma unroll
    for (int k = 0; k < K_N; ++k) wsum += w[k];

    float4 acc = {0.f, 0.f, 0.f, 0.f};
#pragma unroll
    for (int k = 0; k < K_N; ++k) {
        const float4 f = *reinterpret_cast<const float4*>(
            features + (size_t)idx[k] * D_DIM + lane * 4);
        acc.x += w[k] * f.x;
        acc.y += w[k] * f.y;
        acc.z += w[k] * f.z;
        acc.w += w[k] * f.w;
    }

    const float inv = 1.0f / wsum;
    float4 o;
    o.x = acc.x * inv;
    o.y = acc.y * inv;
    o.z = acc.z * inv;
    o.w = acc.w * inv;
    *reinterpret_cast<float4*>(out + (size_t)b * D_DIM + lane * 4) = o;
}

extern "C" void kernel_launch(void* const* d_in, const int* in_sizes, int n_in,
                              void* d_out, int out_size, void* d_ws, size_t ws_size,
                              hipStream_t stream) {
    const float* features  = (const float*)d_in[0];   // [V, D]
    const float* weights   = (const float*)d_in[1];   // [B, K]
    const int*   neigh_idx = (const int*)d_in[2];     // [B, K]
    float*       out       = (float*)d_out;           // [B, D]

    const int B = in_sizes[1] / K_N;                  // 100000

    const int rows_per_block = 8;                     // 256 threads / 32 lanes
    const int grid = (B + rows_per_block - 1) / rows_per_block;

    WeightedAggregator_kernel<<<grid, 256, 0, stream>>>(
        features, weights, neigh_idx, out, B);
}